// Round 1
// baseline (645.509 us; speedup 1.0000x reference)
//
#include <hip/hip_runtime.h>
#include <math.h>
#include <stdint.h>

#define N_NODES 100000
#define N_EDGES 1600000
#define IN_DIM  256
#define HID     128
#define EPS_C   0.3f
#define NB_SCAN 391   // ceil(N_NODES / 256)

// ---------------------------------------------------------------------------
// 1) Count incoming edges per dst, record each edge's slot within its dst row.
// ---------------------------------------------------------------------------
__global__ __launch_bounds__(256) void count_kernel(const int* __restrict__ src,
                                                    const int* __restrict__ dst,
                                                    int* __restrict__ cnt,
                                                    int* __restrict__ slot) {
    int e = blockIdx.x * 256 + threadIdx.x;
    if (e >= N_EDGES) return;
    slot[e] = atomicAdd(&cnt[dst[e]], 1);
    (void)src;
}

// norm = clip(deg,1)^-0.5
__global__ __launch_bounds__(256) void norm_kernel(const int* __restrict__ cnt,
                                                   float* __restrict__ nrm) {
    int i = blockIdx.x * 256 + threadIdx.x;
    if (i >= N_NODES) return;
    nrm[i] = rsqrtf(fmaxf((float)cnt[i], 1.0f));
}

// ---------------------------------------------------------------------------
// 2) Exclusive scan of cnt -> rowstart (3 kernels).
// ---------------------------------------------------------------------------
__global__ __launch_bounds__(256) void block_sum_kernel(const int* __restrict__ cnt,
                                                        int* __restrict__ bsum) {
    __shared__ int s[256];
    int t = threadIdx.x;
    int i = blockIdx.x * 256 + t;
    s[t] = (i < N_NODES) ? cnt[i] : 0;
    __syncthreads();
    for (int off = 128; off > 0; off >>= 1) {
        if (t < off) s[t] += s[t + off];
        __syncthreads();
    }
    if (t == 0) bsum[blockIdx.x] = s[0];
}

__global__ __launch_bounds__(512) void scan_bsum_kernel(int* __restrict__ bsum) {
    __shared__ int s[512];
    int t = threadIdx.x;
    int v = (t < NB_SCAN) ? bsum[t] : 0;
    s[t] = v;
    __syncthreads();
    for (int off = 1; off < 512; off <<= 1) {
        int a = (t >= off) ? s[t - off] : 0;
        __syncthreads();
        s[t] += a;
        __syncthreads();
    }
    if (t < NB_SCAN) bsum[t] = s[t] - v;  // exclusive
}

__global__ __launch_bounds__(256) void scan_block_kernel(const int* __restrict__ cnt,
                                                         const int* __restrict__ bsum,
                                                         int* __restrict__ rowstart) {
    __shared__ int s[256];
    int t = threadIdx.x;
    int i = blockIdx.x * 256 + t;
    int v = (i < N_NODES) ? cnt[i] : 0;
    s[t] = v;
    __syncthreads();
    for (int off = 1; off < 256; off <<= 1) {
        int a = (t >= off) ? s[t - off] : 0;
        __syncthreads();
        s[t] += a;
        __syncthreads();
    }
    if (i < N_NODES) rowstart[i] = bsum[blockIdx.x] + s[t] - v;
    if (i == 0) rowstart[N_NODES] = N_EDGES;
}

// ---------------------------------------------------------------------------
// 3) GEMM: h = relu(x @ w1^T + b1); fused epilogue computes a_dst/a_src.
//    64x128 tile, BK=32, 256 threads, 4x8 micro-tile per thread.
// ---------------------------------------------------------------------------
__global__ __launch_bounds__(256) void gemm_kernel(const float* __restrict__ x,
                                                   const float* __restrict__ w1,
                                                   const float* __restrict__ b1,
                                                   const float* __restrict__ gw,
                                                   float* __restrict__ h,
                                                   float* __restrict__ adst,
                                                   float* __restrict__ asrc) {
    __shared__ float As[64][33];    // [m][k], +1 pad
    __shared__ float Bs[32][132];   // [k][n], +4 pad (keeps rows 16B-aligned)

    int tid = threadIdx.x;
    int tx = tid & 15;    // n-dim: 16 groups of 8 channels
    int ty = tid >> 4;    // m-dim: 16 groups of 4 nodes
    int bm = blockIdx.x * 64;

    float acc[4][8];
#pragma unroll
    for (int i = 0; i < 4; i++)
#pragma unroll
        for (int j = 0; j < 8; j++) acc[i][j] = 0.0f;

    for (int k0 = 0; k0 < IN_DIM; k0 += 32) {
        // stage x tile: 64x32, coalesced (consecutive tid -> consecutive k)
#pragma unroll
        for (int i = 0; i < 8; i++) {
            int idx = i * 256 + tid;
            int m = idx >> 5, k = idx & 31;
            int gm = bm + m;
            As[m][k] = (gm < N_NODES) ? x[gm * IN_DIM + k0 + k] : 0.0f;
        }
        // stage w1 tile: 128x32 -> Bs[k][n], coalesced global read
#pragma unroll
        for (int i = 0; i < 16; i++) {
            int idx = i * 256 + tid;
            int n = idx >> 5, k = idx & 31;
            Bs[k][n] = w1[n * IN_DIM + k0 + k];
        }
        __syncthreads();
#pragma unroll
        for (int k = 0; k < 32; k++) {
            float a[4];
#pragma unroll
            for (int i = 0; i < 4; i++) a[i] = As[ty * 4 + i][k];
            float4 bl = *(const float4*)&Bs[k][tx * 8];
            float4 bh = *(const float4*)&Bs[k][tx * 8 + 4];
            float b[8] = {bl.x, bl.y, bl.z, bl.w, bh.x, bh.y, bh.z, bh.w};
#pragma unroll
            for (int i = 0; i < 4; i++)
#pragma unroll
                for (int j = 0; j < 8; j++) acc[i][j] = fmaf(a[i], b[j], acc[i][j]);
        }
        __syncthreads();
    }

    // epilogue: bias + relu, store h, fused gate dots
    float bias[8], wdv[8], wsv[8];
#pragma unroll
    for (int j = 0; j < 8; j++) {
        bias[j] = b1[tx * 8 + j];
        wdv[j]  = gw[tx * 8 + j];          // w_d
        wsv[j]  = gw[HID + tx * 8 + j];    // w_s
    }
#pragma unroll
    for (int i = 0; i < 4; i++) {
        int gm = bm + ty * 4 + i;
        // gm is uniform across each 16-lane shuffle group (same ty), so the
        // branch + shfl below is group-uniform and safe.
        if (gm < N_NODES) {
            float hr[8];
            float pd = 0.0f, ps = 0.0f;
#pragma unroll
            for (int j = 0; j < 8; j++) {
                float v = fmaxf(acc[i][j] + bias[j], 0.0f);
                hr[j] = v;
                pd = fmaf(v, wdv[j], pd);
                ps = fmaf(v, wsv[j], ps);
            }
            float4 v0 = {hr[0], hr[1], hr[2], hr[3]};
            float4 v1 = {hr[4], hr[5], hr[6], hr[7]};
            *(float4*)&h[gm * HID + tx * 8]     = v0;
            *(float4*)&h[gm * HID + tx * 8 + 4] = v1;
            // reduce across the 16 tx lanes (lane bits 0..3)
#pragma unroll
            for (int m = 1; m < 16; m <<= 1) {
                pd += __shfl_xor(pd, m);
                ps += __shfl_xor(ps, m);
            }
            if (tx == 0) {
                adst[gm] = pd;
                asrc[gm] = ps;
            }
        }
    }
}

// ---------------------------------------------------------------------------
// 4) Scatter edges into CSR order; compute per-edge coefficient ONCE here.
// ---------------------------------------------------------------------------
__global__ __launch_bounds__(256) void scatter_kernel(const int* __restrict__ src,
                                                      const int* __restrict__ dst,
                                                      const int* __restrict__ slot,
                                                      const int* __restrict__ rowstart,
                                                      const float* __restrict__ adst,
                                                      const float* __restrict__ asrc,
                                                      const float* __restrict__ nrm,
                                                      const float* __restrict__ gb,
                                                      int* __restrict__ csrc,
                                                      float* __restrict__ ccoef) {
    int e = blockIdx.x * 256 + threadIdx.x;
    if (e >= N_EDGES) return;
    int s = src[e], d = dst[e];
    int pos = rowstart[d] + slot[e];
    float g = tanhf(adst[d] + asrc[s] + gb[0]);
    csrc[pos]  = s;
    ccoef[pos] = g * nrm[d] * nrm[s];
}

// ---------------------------------------------------------------------------
// 5) Aggregate: one wave per dst node, no atomics.
//    out[d] = EPS*h[d] + sum_{edges} coef * h[src]
// ---------------------------------------------------------------------------
__global__ __launch_bounds__(256) void aggregate_kernel(const int* __restrict__ rowstart,
                                                        const int* __restrict__ csrc,
                                                        const float* __restrict__ ccoef,
                                                        const float* __restrict__ h,
                                                        float* __restrict__ out) {
    int node = blockIdx.x * 4 + (threadIdx.x >> 6);
    if (node >= N_NODES) return;
    int lane = threadIdx.x & 63;

    int beg = rowstart[node];
    int end = rowstart[node + 1];

    float2 acc = {0.0f, 0.0f};
    for (int j = beg; j < end; ++j) {
        int s   = csrc[j];    // wave-uniform -> scalar load
        float c = ccoef[j];   // wave-uniform -> scalar load
        float2 hv = *(const float2*)&h[s * HID + lane * 2];
        acc.x = fmaf(c, hv.x, acc.x);
        acc.y = fmaf(c, hv.y, acc.y);
    }
    float2 hd = *(const float2*)&h[node * HID + lane * 2];
    float2 o;
    o.x = fmaf(EPS_C, hd.x, acc.x);
    o.y = fmaf(EPS_C, hd.y, acc.y);
    *(float2*)&out[node * HID + lane * 2] = o;
}

// ---------------------------------------------------------------------------
extern "C" void kernel_launch(void* const* d_in, const int* in_sizes, int n_in,
                              void* d_out, int out_size, void* d_ws, size_t ws_size,
                              hipStream_t stream) {
    const float* x  = (const float*)d_in[0];
    const int*   ei = (const int*)d_in[1];
    const float* w1 = (const float*)d_in[2];
    const float* b1 = (const float*)d_in[3];
    const float* gw = (const float*)d_in[4];
    const float* gb = (const float*)d_in[5];
    float* out = (float*)d_out;

    const int* src = ei;
    const int* dst = ei + N_EDGES;

    // workspace carve-up (256B aligned)
    uintptr_t base = (uintptr_t)d_ws;
    size_t off = 0;
    auto alloc = [&](size_t bytes) -> void* {
        void* p = (void*)(base + off);
        off += (bytes + 255) & ~(size_t)255;
        return p;
    };
    float* h        = (float*)alloc((size_t)N_NODES * HID * 4);   // 51.2 MB
    float* adst     = (float*)alloc((size_t)N_NODES * 4);
    float* asrc     = (float*)alloc((size_t)N_NODES * 4);
    float* nrm      = (float*)alloc((size_t)N_NODES * 4);
    int*   cnt      = (int*)alloc((size_t)N_NODES * 4);
    int*   rowstart = (int*)alloc((size_t)(N_NODES + 1) * 4);
    int*   slot     = (int*)alloc((size_t)N_EDGES * 4);
    int*   csrc     = (int*)alloc((size_t)N_EDGES * 4);
    float* ccoef    = (float*)alloc((size_t)N_EDGES * 4);
    int*   bsum     = (int*)alloc((size_t)NB_SCAN * 4);

    hipMemsetAsync(cnt, 0, (size_t)N_NODES * 4, stream);

    count_kernel<<<N_EDGES / 256, 256, 0, stream>>>(src, dst, cnt, slot);
    norm_kernel<<<(N_NODES + 255) / 256, 256, 0, stream>>>(cnt, nrm);
    block_sum_kernel<<<NB_SCAN, 256, 0, stream>>>(cnt, bsum);
    scan_bsum_kernel<<<1, 512, 0, stream>>>(bsum);
    scan_block_kernel<<<NB_SCAN, 256, 0, stream>>>(cnt, bsum, rowstart);
    gemm_kernel<<<(N_NODES + 63) / 64, 256, 0, stream>>>(x, w1, b1, gw, h, adst, asrc);
    scatter_kernel<<<(N_EDGES + 255) / 256, 256, 0, stream>>>(src, dst, slot, rowstart,
                                                              adst, asrc, nrm, gb, csrc, ccoef);
    aggregate_kernel<<<(N_NODES + 3) / 4, 256, 0, stream>>>(rowstart, csrc, ccoef, h, out);
}

// Round 2
// 419.100 us; speedup vs baseline: 1.5402x; 1.5402x over previous
//
#include <hip/hip_runtime.h>
#include <math.h>
#include <stdint.h>

#define N_NODES 100000
#define N_EDGES 1600000
#define IN_DIM  256
#define HID     128
#define EPS_C   0.3f
#define NB_SCAN 391   // ceil(N_NODES / 256)

typedef __attribute__((ext_vector_type(8))) __bf16 bf16x8;
typedef __attribute__((ext_vector_type(4))) float  f32x4;
typedef __attribute__((ext_vector_type(8))) unsigned short ushort8;

// round-to-nearest-even f32 -> bf16 (values are finite; no NaN handling needed)
static __device__ __forceinline__ unsigned short f2bf(float f) {
    unsigned u = __float_as_uint(f);
    unsigned r = (u + 0x7fffu + ((u >> 16) & 1u)) >> 16;
    return (unsigned short)r;
}
static __device__ __forceinline__ float2 bf2_to_f2(unsigned u) {
    float2 r;
    r.x = __uint_as_float((u & 0xffffu) << 16);
    r.y = __uint_as_float(u & 0xffff0000u);
    return r;
}

// ---------------------------------------------------------------------------
// 1) Count incoming edges per dst, record each edge's slot within its dst row.
// ---------------------------------------------------------------------------
__global__ __launch_bounds__(256) void count_kernel(const int* __restrict__ dst,
                                                    int* __restrict__ cnt,
                                                    int* __restrict__ slot) {
    int e = blockIdx.x * 256 + threadIdx.x;
    if (e >= N_EDGES) return;
    slot[e] = atomicAdd(&cnt[dst[e]], 1);
}

__global__ __launch_bounds__(256) void norm_kernel(const int* __restrict__ cnt,
                                                   float* __restrict__ nrm) {
    int i = blockIdx.x * 256 + threadIdx.x;
    if (i >= N_NODES) return;
    nrm[i] = rsqrtf(fmaxf((float)cnt[i], 1.0f));
}

// ---------------------------------------------------------------------------
// 2) Exclusive scan of cnt -> rowstart (3 kernels).
// ---------------------------------------------------------------------------
__global__ __launch_bounds__(256) void block_sum_kernel(const int* __restrict__ cnt,
                                                        int* __restrict__ bsum) {
    __shared__ int s[256];
    int t = threadIdx.x;
    int i = blockIdx.x * 256 + t;
    s[t] = (i < N_NODES) ? cnt[i] : 0;
    __syncthreads();
    for (int off = 128; off > 0; off >>= 1) {
        if (t < off) s[t] += s[t + off];
        __syncthreads();
    }
    if (t == 0) bsum[blockIdx.x] = s[0];
}

__global__ __launch_bounds__(512) void scan_bsum_kernel(int* __restrict__ bsum) {
    __shared__ int s[512];
    int t = threadIdx.x;
    int v = (t < NB_SCAN) ? bsum[t] : 0;
    s[t] = v;
    __syncthreads();
    for (int off = 1; off < 512; off <<= 1) {
        int a = (t >= off) ? s[t - off] : 0;
        __syncthreads();
        s[t] += a;
        __syncthreads();
    }
    if (t < NB_SCAN) bsum[t] = s[t] - v;  // exclusive
}

__global__ __launch_bounds__(256) void scan_block_kernel(const int* __restrict__ cnt,
                                                         const int* __restrict__ bsum,
                                                         int* __restrict__ rowstart) {
    __shared__ int s[256];
    int t = threadIdx.x;
    int i = blockIdx.x * 256 + t;
    int v = (i < N_NODES) ? cnt[i] : 0;
    s[t] = v;
    __syncthreads();
    for (int off = 1; off < 256; off <<= 1) {
        int a = (t >= off) ? s[t - off] : 0;
        __syncthreads();
        s[t] += a;
        __syncthreads();
    }
    if (i < N_NODES) rowstart[i] = bsum[blockIdx.x] + s[t] - v;
    if (i == 0) rowstart[N_NODES] = N_EDGES;
}

// ---------------------------------------------------------------------------
// 3) MFMA GEMM: h = relu(x @ w1^T + b1), bf16 inputs converted in-register,
//    h stored as bf16. Fused gate dots -> {a_dst,nrm} / {a_src,nrm} packs.
//    Block = 256 thr (4 waves), tile M=64 N=128, BK=32, 16x16x32 MFMA.
//    LDS rows padded to 40 ushorts (80 B) so 16-lane b128 frag reads cover
//    all 32 banks in 8 lanes (2-way aliasing = free).
// ---------------------------------------------------------------------------
__global__ __launch_bounds__(256) void gemm_kernel(const float* __restrict__ x,
                                                   const float* __restrict__ w1,
                                                   const float* __restrict__ b1,
                                                   const float* __restrict__ gw,
                                                   const float* __restrict__ nrm,
                                                   unsigned short* __restrict__ h,
                                                   float2* __restrict__ pd_pack,
                                                   float2* __restrict__ ps_pack) {
    __shared__ unsigned short As[64 * 40];   // [m][k] bf16, stride 40
    __shared__ unsigned short Bs[128 * 40];  // [n][k] bf16, stride 40

    int tid = threadIdx.x;
    int bm = blockIdx.x * 64;

    int wv   = tid >> 6;    // wave 0..3 -> rows [wv*16, wv*16+16)
    int lane = tid & 63;
    int col  = lane & 15;
    int kq   = lane >> 4;   // k-quad

    f32x4 acc[8];
#pragma unroll
    for (int nf = 0; nf < 8; nf++) acc[nf] = (f32x4){0.f, 0.f, 0.f, 0.f};

    // staging coords
    int am = tid >> 2;            // 0..63
    int ak = (tid & 3) * 8;       // 0,8,16,24
    int bn = tid >> 1;            // 0..127
    int bk = (tid & 1) * 16;      // 0,16
    int agm = bm + am;

    for (int k0 = 0; k0 < IN_DIM; k0 += 32) {
        // ---- stage A: 64x32 f32 -> bf16 (8 floats/thread)
        float4 a0 = {0,0,0,0}, a1 = {0,0,0,0};
        if (agm < N_NODES) {
            const float* p = &x[agm * IN_DIM + k0 + ak];
            a0 = *(const float4*)p;
            a1 = *(const float4*)(p + 4);
        }
        ushort8 av;
        av[0]=f2bf(a0.x); av[1]=f2bf(a0.y); av[2]=f2bf(a0.z); av[3]=f2bf(a0.w);
        av[4]=f2bf(a1.x); av[5]=f2bf(a1.y); av[6]=f2bf(a1.z); av[7]=f2bf(a1.w);
        // ---- stage B: 128x32 f32 -> bf16 (16 floats/thread)
        const float* q = &w1[bn * IN_DIM + k0 + bk];
        float4 b0 = *(const float4*)q;
        float4 b1v = *(const float4*)(q + 4);
        float4 b2 = *(const float4*)(q + 8);
        float4 b3 = *(const float4*)(q + 12);
        ushort8 bv0, bv1;
        bv0[0]=f2bf(b0.x); bv0[1]=f2bf(b0.y); bv0[2]=f2bf(b0.z); bv0[3]=f2bf(b0.w);
        bv0[4]=f2bf(b1v.x); bv0[5]=f2bf(b1v.y); bv0[6]=f2bf(b1v.z); bv0[7]=f2bf(b1v.w);
        bv1[0]=f2bf(b2.x); bv1[1]=f2bf(b2.y); bv1[2]=f2bf(b2.z); bv1[3]=f2bf(b2.w);
        bv1[4]=f2bf(b3.x); bv1[5]=f2bf(b3.y); bv1[6]=f2bf(b3.z); bv1[7]=f2bf(b3.w);

        __syncthreads();  // protect LDS reuse from previous iter
        *(ushort8*)&As[am * 40 + ak] = av;
        *(ushort8*)&Bs[bn * 40 + bk] = bv0;
        *(ushort8*)&Bs[bn * 40 + bk + 8] = bv1;
        __syncthreads();

        // ---- MFMA: each wave does 16 rows x 128 cols
        bf16x8 afrag = *(bf16x8*)&As[(wv * 16 + col) * 40 + kq * 8];
#pragma unroll
        for (int nf = 0; nf < 8; nf++) {
            bf16x8 bfrag = *(bf16x8*)&Bs[(nf * 16 + col) * 40 + kq * 8];
            acc[nf] = __builtin_amdgcn_mfma_f32_16x16x32_bf16(afrag, bfrag, acc[nf], 0, 0, 0);
        }
    }

    // ---- epilogue: bias+relu, bf16 h store, fused gate dots
    float bias[8], wd[8], wsv[8];
#pragma unroll
    for (int nf = 0; nf < 8; nf++) {
        bias[nf] = b1[nf * 16 + col];
        wd[nf]   = gw[nf * 16 + col];
        wsv[nf]  = gw[HID + nf * 16 + col];
    }
#pragma unroll
    for (int r = 0; r < 4; r++) {
        int gm = bm + wv * 16 + kq * 4 + r;   // uniform across the 16 col-lanes
        float pd = 0.f, ps = 0.f;
        bool ok = (gm < N_NODES);
#pragma unroll
        for (int nf = 0; nf < 8; nf++) {
            float v = fmaxf(acc[nf][r] + bias[nf], 0.f);
            pd = fmaf(v, wd[nf], pd);
            ps = fmaf(v, wsv[nf], ps);
            if (ok) h[gm * HID + nf * 16 + col] = f2bf(v);
        }
        // reduce over the 16 col lanes (lane bits 0..3)
#pragma unroll
        for (int m = 1; m < 16; m <<= 1) {
            pd += __shfl_xor(pd, m);
            ps += __shfl_xor(ps, m);
        }
        if (ok && col == 0) {
            float nv = nrm[gm];
            pd_pack[gm] = make_float2(pd, nv);
            ps_pack[gm] = make_float2(ps, nv);
        }
    }
}

// ---------------------------------------------------------------------------
// 4) Scatter edges into CSR order; per-edge coefficient computed once.
//    epack[pos] = {src, coef}
// ---------------------------------------------------------------------------
__global__ __launch_bounds__(256) void scatter_kernel(const int* __restrict__ src,
                                                      const int* __restrict__ dst,
                                                      const int* __restrict__ slot,
                                                      const int* __restrict__ rowstart,
                                                      const float2* __restrict__ pd_pack,
                                                      const float2* __restrict__ ps_pack,
                                                      const float* __restrict__ gb,
                                                      int2* __restrict__ epack) {
    int e = blockIdx.x * 256 + threadIdx.x;
    if (e >= N_EDGES) return;
    int s = src[e], d = dst[e];
    int pos = rowstart[d] + slot[e];
    float2 pdp = pd_pack[d];   // {a_dst[d], nrm[d]}
    float2 psp = ps_pack[s];   // {a_src[s], nrm[s]}
    float g = tanhf(pdp.x + psp.x + gb[0]);
    int2 pk;
    pk.x = s;
    pk.y = __float_as_int(g * pdp.y * psp.y);
    epack[pos] = pk;
}

// ---------------------------------------------------------------------------
// 5) Aggregate: one wave per dst node, no atomics.
//    out[d] = EPS*h[d] + sum coef * h[src]   (h is bf16, acc in f32)
// ---------------------------------------------------------------------------
__global__ __launch_bounds__(256) void aggregate_kernel(const int* __restrict__ rowstart,
                                                        const int2* __restrict__ epack,
                                                        const unsigned short* __restrict__ h,
                                                        float* __restrict__ out) {
    int node = blockIdx.x * 4 + (threadIdx.x >> 6);
    if (node >= N_NODES) return;
    int lane = threadIdx.x & 63;

    int beg = rowstart[node];
    int end = rowstart[node + 1];

    float ax = 0.f, ay = 0.f;
    int j = beg;
    for (; j + 1 < end; j += 2) {
        int2 e0 = epack[j];
        int2 e1 = epack[j + 1];
        unsigned u0 = *(const unsigned*)&h[e0.x * HID + lane * 2];
        unsigned u1 = *(const unsigned*)&h[e1.x * HID + lane * 2];
        float c0 = __int_as_float(e0.y), c1 = __int_as_float(e1.y);
        float2 h0 = bf2_to_f2(u0), h1 = bf2_to_f2(u1);
        ax = fmaf(c0, h0.x, ax); ay = fmaf(c0, h0.y, ay);
        ax = fmaf(c1, h1.x, ax); ay = fmaf(c1, h1.y, ay);
    }
    if (j < end) {
        int2 e0 = epack[j];
        unsigned u0 = *(const unsigned*)&h[e0.x * HID + lane * 2];
        float c0 = __int_as_float(e0.y);
        float2 h0 = bf2_to_f2(u0);
        ax = fmaf(c0, h0.x, ax); ay = fmaf(c0, h0.y, ay);
    }
    unsigned ud = *(const unsigned*)&h[node * HID + lane * 2];
    float2 hd = bf2_to_f2(ud);
    float2 o;
    o.x = fmaf(EPS_C, hd.x, ax);
    o.y = fmaf(EPS_C, hd.y, ay);
    *(float2*)&out[node * HID + lane * 2] = o;
}

// ---------------------------------------------------------------------------
extern "C" void kernel_launch(void* const* d_in, const int* in_sizes, int n_in,
                              void* d_out, int out_size, void* d_ws, size_t ws_size,
                              hipStream_t stream) {
    const float* x  = (const float*)d_in[0];
    const int*   ei = (const int*)d_in[1];
    const float* w1 = (const float*)d_in[2];
    const float* b1 = (const float*)d_in[3];
    const float* gw = (const float*)d_in[4];
    const float* gb = (const float*)d_in[5];
    float* out = (float*)d_out;

    const int* src = ei;
    const int* dst = ei + N_EDGES;

    uintptr_t base = (uintptr_t)d_ws;
    size_t off = 0;
    auto alloc = [&](size_t bytes) -> void* {
        void* p = (void*)(base + off);
        off += (bytes + 255) & ~(size_t)255;
        return p;
    };
    unsigned short* h   = (unsigned short*)alloc((size_t)N_NODES * HID * 2);  // 25.6 MB
    float2* pd_pack     = (float2*)alloc((size_t)N_NODES * 8);
    float2* ps_pack     = (float2*)alloc((size_t)N_NODES * 8);
    float*  nrm         = (float*)alloc((size_t)N_NODES * 4);
    int*    cnt         = (int*)alloc((size_t)N_NODES * 4);
    int*    rowstart    = (int*)alloc((size_t)(N_NODES + 1) * 4);
    int*    slot        = (int*)alloc((size_t)N_EDGES * 4);
    int2*   epack       = (int2*)alloc((size_t)N_EDGES * 8);
    int*    bsum        = (int*)alloc((size_t)NB_SCAN * 4);

    hipMemsetAsync(cnt, 0, (size_t)N_NODES * 4, stream);

    count_kernel<<<N_EDGES / 256, 256, 0, stream>>>(dst, cnt, slot);
    norm_kernel<<<(N_NODES + 255) / 256, 256, 0, stream>>>(cnt, nrm);
    block_sum_kernel<<<NB_SCAN, 256, 0, stream>>>(cnt, bsum);
    scan_bsum_kernel<<<1, 512, 0, stream>>>(bsum);
    scan_block_kernel<<<NB_SCAN, 256, 0, stream>>>(cnt, bsum, rowstart);
    gemm_kernel<<<(N_NODES + 63) / 64, 256, 0, stream>>>(x, w1, b1, gw, nrm,
                                                         h, pd_pack, ps_pack);
    scatter_kernel<<<(N_EDGES + 255) / 256, 256, 0, stream>>>(src, dst, slot, rowstart,
                                                              pd_pack, ps_pack, gb, epack);
    aggregate_kernel<<<(N_NODES + 3) / 4, 256, 0, stream>>>(rowstart, epack, h, out);
}

// Round 4
// 412.053 us; speedup vs baseline: 1.5666x; 1.0171x over previous
//
#include <hip/hip_runtime.h>
#include <math.h>
#include <stdint.h>

#define N_NODES 100000
#define N_EDGES 1600000
#define IN_DIM  256
#define HID     128
#define EPS_C   0.3f
#define NB_SCAN 391   // ceil(N_NODES / 256)

typedef __attribute__((ext_vector_type(8))) __bf16 bf16x8;
typedef __attribute__((ext_vector_type(4))) float  f32x4;
typedef __attribute__((ext_vector_type(8))) unsigned short ushort8;

static __device__ __forceinline__ unsigned short f2bf(float f) {
    unsigned u = __float_as_uint(f);
    unsigned r = (u + 0x7fffu + ((u >> 16) & 1u)) >> 16;
    return (unsigned short)r;
}
static __device__ __forceinline__ float bf2f(unsigned short s) {
    return __uint_as_float((unsigned)s << 16);
}
// branch-free tanh: 1 - 2/(exp2(2x*log2e)+1); correct limits at +-inf
static __device__ __forceinline__ float fast_tanh(float x) {
    float e = __builtin_exp2f(x * 2.8853900817779268f);  // 2*log2(e)
    return 1.0f - 2.0f / (e + 1.0f);
}

// ---------------------------------------------------------------------------
// 1) Count incoming edges per dst (4 edges/thread, int4 reads).
// ---------------------------------------------------------------------------
__global__ __launch_bounds__(256) void count_kernel(const int* __restrict__ dst,
                                                    int* __restrict__ cnt) {
    int i = blockIdx.x * 256 + threadIdx.x;
    if (i * 4 >= N_EDGES) return;
    int4 d = *(const int4*)&dst[i * 4];
    atomicAdd(&cnt[d.x], 1);
    atomicAdd(&cnt[d.y], 1);
    atomicAdd(&cnt[d.z], 1);
    atomicAdd(&cnt[d.w], 1);
}

// ---------------------------------------------------------------------------
// 2) Exclusive scan of cnt -> rowstart; fused: nrm write + cnt zeroing
//    (zeroed cnt is reused by scatter as the slot counter).
// ---------------------------------------------------------------------------
__global__ __launch_bounds__(256) void block_sum_kernel(const int* __restrict__ cnt,
                                                        int* __restrict__ bsum) {
    __shared__ int s[256];
    int t = threadIdx.x;
    int i = blockIdx.x * 256 + t;
    s[t] = (i < N_NODES) ? cnt[i] : 0;
    __syncthreads();
    for (int off = 128; off > 0; off >>= 1) {
        if (t < off) s[t] += s[t + off];
        __syncthreads();
    }
    if (t == 0) bsum[blockIdx.x] = s[0];
}

__global__ __launch_bounds__(512) void scan_bsum_kernel(int* __restrict__ bsum) {
    __shared__ int s[512];
    int t = threadIdx.x;
    int v = (t < NB_SCAN) ? bsum[t] : 0;
    s[t] = v;
    __syncthreads();
    for (int off = 1; off < 512; off <<= 1) {
        int a = (t >= off) ? s[t - off] : 0;
        __syncthreads();
        s[t] += a;
        __syncthreads();
    }
    if (t < NB_SCAN) bsum[t] = s[t] - v;  // exclusive
}

__global__ __launch_bounds__(256) void scan_block_kernel(int* __restrict__ cnt,
                                                         const int* __restrict__ bsum,
                                                         int* __restrict__ rowstart,
                                                         float* __restrict__ nrm) {
    __shared__ int s[256];
    int t = threadIdx.x;
    int i = blockIdx.x * 256 + t;
    int v = (i < N_NODES) ? cnt[i] : 0;
    s[t] = v;
    __syncthreads();
    for (int off = 1; off < 256; off <<= 1) {
        int a = (t >= off) ? s[t - off] : 0;
        __syncthreads();
        s[t] += a;
        __syncthreads();
    }
    if (i < N_NODES) {
        rowstart[i] = bsum[blockIdx.x] + s[t] - v;
        nrm[i] = rsqrtf(fmaxf((float)v, 1.0f));
        cnt[i] = 0;  // reset: scatter reuses cnt as per-dst slot counter
    }
    if (i == 0) rowstart[N_NODES] = N_EDGES;
}

// ---------------------------------------------------------------------------
// w1 -> bf16 preconvert (one-time tiny kernel, 32768 elems)
// ---------------------------------------------------------------------------
__global__ __launch_bounds__(256) void convert_w1_kernel(const float* __restrict__ w1,
                                                         unsigned short* __restrict__ w1b) {
    int i = blockIdx.x * 256 + threadIdx.x;
    if (i * 4 >= HID * IN_DIM) return;
    float4 v = *(const float4*)&w1[i * 4];
    ushort4 r;
    r.x = f2bf(v.x); r.y = f2bf(v.y); r.z = f2bf(v.z); r.w = f2bf(v.w);
    *(ushort4*)&w1b[i * 4] = r;
}

// ---------------------------------------------------------------------------
// 3) MFMA GEMM: h = relu(x @ w1^T + b1), bf16, fused gate dots.
//    Block = 256 thr (4 waves), tile M=64 N=128, BK=32, 16x16x32 MFMA.
// ---------------------------------------------------------------------------
__global__ __launch_bounds__(256) void gemm_kernel(const float* __restrict__ x,
                                                   const unsigned short* __restrict__ w1b,
                                                   const float* __restrict__ b1,
                                                   const float* __restrict__ gw,
                                                   const float* __restrict__ nrm,
                                                   unsigned short* __restrict__ h,
                                                   float2* __restrict__ pd_pack,
                                                   float2* __restrict__ ps_pack) {
    __shared__ unsigned short As[64 * 40];   // [m][k] bf16, stride 40
    __shared__ unsigned short Bs[128 * 40];  // [n][k] bf16, stride 40

    int tid = threadIdx.x;
    int bm = blockIdx.x * 64;

    int wv   = tid >> 6;
    int lane = tid & 63;
    int col  = lane & 15;
    int kq   = lane >> 4;

    f32x4 acc[8];
#pragma unroll
    for (int nf = 0; nf < 8; nf++) acc[nf] = (f32x4){0.f, 0.f, 0.f, 0.f};

    int am = tid >> 2;            // 0..63
    int ak = (tid & 3) * 8;       // 0,8,16,24
    int bn = tid >> 1;            // 0..127
    int bk = (tid & 1) * 16;      // 0,16
    int agm = bm + am;

    for (int k0 = 0; k0 < IN_DIM; k0 += 32) {
        // stage A: 64x32 f32 -> bf16 (8 floats/thread)
        float4 a0 = {0,0,0,0}, a1 = {0,0,0,0};
        if (agm < N_NODES) {
            const float* p = &x[agm * IN_DIM + k0 + ak];
            a0 = *(const float4*)p;
            a1 = *(const float4*)(p + 4);
        }
        ushort8 av;
        av[0]=f2bf(a0.x); av[1]=f2bf(a0.y); av[2]=f2bf(a0.z); av[3]=f2bf(a0.w);
        av[4]=f2bf(a1.x); av[5]=f2bf(a1.y); av[6]=f2bf(a1.z); av[7]=f2bf(a1.w);
        // stage B: already bf16 (16 elems = 2 x ushort8 per thread, no convert)
        ushort8 bv0 = *(const ushort8*)&w1b[bn * IN_DIM + k0 + bk];
        ushort8 bv1 = *(const ushort8*)&w1b[bn * IN_DIM + k0 + bk + 8];

        __syncthreads();
        *(ushort8*)&As[am * 40 + ak] = av;
        *(ushort8*)&Bs[bn * 40 + bk] = bv0;
        *(ushort8*)&Bs[bn * 40 + bk + 8] = bv1;
        __syncthreads();

        bf16x8 afrag = *(bf16x8*)&As[(wv * 16 + col) * 40 + kq * 8];
#pragma unroll
        for (int nf = 0; nf < 8; nf++) {
            bf16x8 bfrag = *(bf16x8*)&Bs[(nf * 16 + col) * 40 + kq * 8];
            acc[nf] = __builtin_amdgcn_mfma_f32_16x16x32_bf16(afrag, bfrag, acc[nf], 0, 0, 0);
        }
    }

    float bias[8], wd[8], wsv[8];
#pragma unroll
    for (int nf = 0; nf < 8; nf++) {
        bias[nf] = b1[nf * 16 + col];
        wd[nf]   = gw[nf * 16 + col];
        wsv[nf]  = gw[HID + nf * 16 + col];
    }
#pragma unroll
    for (int r = 0; r < 4; r++) {
        int gm = bm + wv * 16 + kq * 4 + r;   // uniform across the 16 col-lanes
        float pd = 0.f, ps = 0.f;
        bool ok = (gm < N_NODES);
#pragma unroll
        for (int nf = 0; nf < 8; nf++) {
            float v = fmaxf(acc[nf][r] + bias[nf], 0.f);
            pd = fmaf(v, wd[nf], pd);
            ps = fmaf(v, wsv[nf], ps);
            if (ok) h[gm * HID + nf * 16 + col] = f2bf(v);
        }
#pragma unroll
        for (int m = 1; m < 16; m <<= 1) {
            pd += __shfl_xor(pd, m);
            ps += __shfl_xor(ps, m);
        }
        if (ok && col == 0) {
            float nv = nrm[gm];
            pd_pack[gm] = make_float2(pd, nv);
            ps_pack[gm] = make_float2(ps, nv);
        }
    }
}

// ---------------------------------------------------------------------------
// 4) Scatter edges into CSR order; slot via atomic on (zeroed) cnt.
//    epack[pos] = {src, coef}
// ---------------------------------------------------------------------------
__global__ __launch_bounds__(256) void scatter_kernel(const int* __restrict__ src,
                                                      const int* __restrict__ dst,
                                                      int* __restrict__ cnt,
                                                      const int* __restrict__ rowstart,
                                                      const float2* __restrict__ pd_pack,
                                                      const float2* __restrict__ ps_pack,
                                                      const float* __restrict__ gb,
                                                      int2* __restrict__ epack) {
    int e = blockIdx.x * 256 + threadIdx.x;
    if (e >= N_EDGES) return;
    int s = src[e], d = dst[e];
    int pos = rowstart[d] + atomicAdd(&cnt[d], 1);
    float2 pdp = pd_pack[d];   // {a_dst[d], nrm[d]}
    float2 psp = ps_pack[s];   // {a_src[s], nrm[s]}
    float g = fast_tanh(pdp.x + psp.x + gb[0]);
    int2 pk;
    pk.x = s;
    pk.y = __float_as_int(g * pdp.y * psp.y);
    epack[pos] = pk;
}

// ---------------------------------------------------------------------------
// 5) Aggregate: one wave per dst node; 4 edges in parallel per wave
//    (16 lanes x 8 channels each), unroll 2 -> 8 h-rows in flight.
// ---------------------------------------------------------------------------
__global__ __launch_bounds__(256) void aggregate_kernel(const int* __restrict__ rowstart,
                                                        const int2* __restrict__ epack,
                                                        const unsigned short* __restrict__ h,
                                                        float* __restrict__ out) {
    int node = blockIdx.x * 4 + (threadIdx.x >> 6);
    if (node >= N_NODES) return;
    int lane = threadIdx.x & 63;
    int q  = lane >> 4;    // 0..3: edge slot within wave
    int ql = lane & 15;    // channel group: ch = ql*8

    int beg = rowstart[node];
    int end = rowstart[node + 1];

    float acc[8];
#pragma unroll
    for (int t = 0; t < 8; t++) acc[t] = 0.f;

    int j = beg;
    for (; j + 8 <= end; j += 8) {
        int2 e0 = epack[j + q];
        int2 e1 = epack[j + 4 + q];
        ushort8 r0 = *(const ushort8*)&h[e0.x * HID + ql * 8];
        ushort8 r1 = *(const ushort8*)&h[e1.x * HID + ql * 8];
        float c0 = __int_as_float(e0.y);
        float c1 = __int_as_float(e1.y);
#pragma unroll
        for (int t = 0; t < 8; t++) {
            acc[t] = fmaf(c0, bf2f(r0[t]), acc[t]);
            acc[t] = fmaf(c1, bf2f(r1[t]), acc[t]);
        }
    }
    for (; j < end; j += 4) {
        bool act = (j + q) < end;
        int idx = act ? (j + q) : beg;          // beg valid: j<end => beg<end
        int2 e = epack[idx];
        ushort8 r = *(const ushort8*)&h[e.x * HID + ql * 8];
        float c = act ? __int_as_float(e.y) : 0.f;
#pragma unroll
        for (int t = 0; t < 8; t++) acc[t] = fmaf(c, bf2f(r[t]), acc[t]);
    }
    // combine the 4 edge-slots (lane bits 4,5)
#pragma unroll
    for (int t = 0; t < 8; t++) {
        acc[t] += __shfl_xor(acc[t], 16);
        acc[t] += __shfl_xor(acc[t], 32);
    }
    if (q == 0) {
        ushort8 hd = *(const ushort8*)&h[node * HID + ql * 8];
        f32x4 o0, o1;
        o0.x = fmaf(EPS_C, bf2f(hd[0]), acc[0]);
        o0.y = fmaf(EPS_C, bf2f(hd[1]), acc[1]);
        o0.z = fmaf(EPS_C, bf2f(hd[2]), acc[2]);
        o0.w = fmaf(EPS_C, bf2f(hd[3]), acc[3]);
        o1.x = fmaf(EPS_C, bf2f(hd[4]), acc[4]);
        o1.y = fmaf(EPS_C, bf2f(hd[5]), acc[5]);
        o1.z = fmaf(EPS_C, bf2f(hd[6]), acc[6]);
        o1.w = fmaf(EPS_C, bf2f(hd[7]), acc[7]);
        // nontemporal: out is never re-read; keep h resident in L2 instead
        __builtin_nontemporal_store(o0, (f32x4*)&out[node * HID + ql * 8]);
        __builtin_nontemporal_store(o1, (f32x4*)&out[node * HID + ql * 8 + 4]);
    }
}

// ---------------------------------------------------------------------------
extern "C" void kernel_launch(void* const* d_in, const int* in_sizes, int n_in,
                              void* d_out, int out_size, void* d_ws, size_t ws_size,
                              hipStream_t stream) {
    const float* x  = (const float*)d_in[0];
    const int*   ei = (const int*)d_in[1];
    const float* w1 = (const float*)d_in[2];
    const float* b1 = (const float*)d_in[3];
    const float* gw = (const float*)d_in[4];
    const float* gb = (const float*)d_in[5];
    float* out = (float*)d_out;

    const int* src = ei;
    const int* dst = ei + N_EDGES;

    uintptr_t base = (uintptr_t)d_ws;
    size_t off = 0;
    auto alloc = [&](size_t bytes) -> void* {
        void* p = (void*)(base + off);
        off += (bytes + 255) & ~(size_t)255;
        return p;
    };
    unsigned short* h   = (unsigned short*)alloc((size_t)N_NODES * HID * 2);  // 25.6 MB
    float2* pd_pack     = (float2*)alloc((size_t)N_NODES * 8);
    float2* ps_pack     = (float2*)alloc((size_t)N_NODES * 8);
    float*  nrm         = (float*)alloc((size_t)N_NODES * 4);
    int*    cnt         = (int*)alloc((size_t)N_NODES * 4);
    int*    rowstart    = (int*)alloc((size_t)(N_NODES + 1) * 4);
    int2*   epack       = (int2*)alloc((size_t)N_EDGES * 8);
    int*    bsum        = (int*)alloc((size_t)NB_SCAN * 4);
    unsigned short* w1b = (unsigned short*)alloc((size_t)HID * IN_DIM * 2);

    (void)hipMemsetAsync(cnt, 0, (size_t)N_NODES * 4, stream);

    convert_w1_kernel<<<(HID * IN_DIM / 4 + 255) / 256, 256, 0, stream>>>(w1, w1b);
    count_kernel<<<(N_EDGES / 4 + 255) / 256, 256, 0, stream>>>(dst, cnt);
    block_sum_kernel<<<NB_SCAN, 256, 0, stream>>>(cnt, bsum);
    scan_bsum_kernel<<<1, 512, 0, stream>>>(bsum);
    scan_block_kernel<<<NB_SCAN, 256, 0, stream>>>(cnt, bsum, rowstart, nrm);
    gemm_kernel<<<(N_NODES + 63) / 64, 256, 0, stream>>>(x, w1b, b1, gw, nrm,
                                                         h, pd_pack, ps_pack);
    scatter_kernel<<<(N_EDGES + 255) / 256, 256, 0, stream>>>(src, dst, cnt, rowstart,
                                                              pd_pack, ps_pack, gb, epack);
    aggregate_kernel<<<(N_NODES + 3) / 4, 256, 0, stream>>>(rowstart, epack, h, out);
}